// Round 9
// baseline (31.611 us; speedup 1.0000x reference)
//
#include <hip/hip_runtime.h>
#include <math.h>

#define NC     1000
#define NBLK   4000     // 4 column-quarter blocks per class (grid > 2048 resident slots)
#define DIM    2048
#define QCOLS  512
#define NBATCH 8192
#define MAXN   1024     // sidx capacity; true max class count ~25 (Poisson(8.2))

typedef float f32x2 __attribute__((ext_vector_type(2)));
typedef int   i32x4 __attribute__((ext_vector_type(4)));

// Grid: 4000 blocks = 1000 classes x 4 column quarters; 256 threads (4 waves).
// 8 blocks/CU resident (2048 slots) < 4000 grid -> second dispatch round is
// assigned dynamically to draining CUs = load balancing at FULL occupancy.
// Thread t of block (c,q) owns cols q*512 + [2t, 2t+2).
__global__ __launch_bounds__(256) void k_main(
        const int*   __restrict__ y,
        const float* __restrict__ feat,
        const float* __restrict__ centers,
        float* __restrict__ grad_out,     // d_out + 1 (4B-aligned only)
        float* __restrict__ partials) {   // [4000]
    const int c = blockIdx.x >> 2;
    const int q = blockIdx.x & 3;
    const int t = threadIdx.x;
    const int col = q * QCOLS + 2 * t;

    const f32x2 cen = *(const f32x2*)(centers + (size_t)c * DIM + col);

    __shared__ unsigned short sidx[MAXN];
    __shared__ int scur;
    if (t == 0) scur = 0;
    __syncthreads();

    // scan y (L2-resident): 8 int4 per thread
    const i32x4* y4 = (const i32x4*)y;
    for (int j = t; j < NBATCH / 4; j += 256) {
        i32x4 v = y4[j];
        int base = 4 * j;
        if (v.x == c) sidx[atomicAdd(&scur, 1) & (MAXN - 1)] = (unsigned short)(base + 0);
        if (v.y == c) sidx[atomicAdd(&scur, 1) & (MAXN - 1)] = (unsigned short)(base + 1);
        if (v.z == c) sidx[atomicAdd(&scur, 1) & (MAXN - 1)] = (unsigned short)(base + 2);
        if (v.w == c) sidx[atomicAdd(&scur, 1) & (MAXN - 1)] = (unsigned short)(base + 3);
    }
    __syncthreads();
    const int n = scur;

    f32x2 acc = (f32x2)(0.f);
    f32x2 sq  = (f32x2)(0.f);

    int r = 0;
    for (; r + 8 <= n; r += 8) {
        int i0 = sidx[r+0], i1 = sidx[r+1], i2 = sidx[r+2], i3 = sidx[r+3];
        int i4 = sidx[r+4], i5 = sidx[r+5], i6 = sidx[r+6], i7 = sidx[r+7];
        f32x2 v0 = __builtin_nontemporal_load((const f32x2*)(feat + (size_t)i0 * DIM + col));
        f32x2 v1 = __builtin_nontemporal_load((const f32x2*)(feat + (size_t)i1 * DIM + col));
        f32x2 v2 = __builtin_nontemporal_load((const f32x2*)(feat + (size_t)i2 * DIM + col));
        f32x2 v3 = __builtin_nontemporal_load((const f32x2*)(feat + (size_t)i3 * DIM + col));
        f32x2 v4 = __builtin_nontemporal_load((const f32x2*)(feat + (size_t)i4 * DIM + col));
        f32x2 v5 = __builtin_nontemporal_load((const f32x2*)(feat + (size_t)i5 * DIM + col));
        f32x2 v6 = __builtin_nontemporal_load((const f32x2*)(feat + (size_t)i6 * DIM + col));
        f32x2 v7 = __builtin_nontemporal_load((const f32x2*)(feat + (size_t)i7 * DIM + col));
        acc += v0 + v1 + v2 + v3 + v4 + v5 + v6 + v7;
        f32x2 d0 = v0 - cen, d1 = v1 - cen, d2 = v2 - cen, d3 = v3 - cen;
        f32x2 d4 = v4 - cen, d5 = v5 - cen, d6 = v6 - cen, d7 = v7 - cen;
        sq += d0*d0 + d1*d1 + d2*d2 + d3*d3 + d4*d4 + d5*d5 + d6*d6 + d7*d7;
    }
    for (; r < n; ++r) {
        f32x2 v0 = __builtin_nontemporal_load((const f32x2*)(feat + (size_t)sidx[r] * DIM + col));
        acc += v0;
        f32x2 d0 = v0 - cen;
        sq += d0 * d0;
    }
    float lsum = sq.x + sq.y;

    // grad = coeff * (centers - mean); zero when n == 0
    f32x2 g = (f32x2)(0.f);
    if (n > 0) {
        float fn = (float)n;
        float coeff = fn / (1.0f + fn);
        g = coeff * (cen - acc * (1.0f / fn));
    }
    float* go = grad_out + (size_t)c * DIM + col;   // odd base -> scalar NT stores
    __builtin_nontemporal_store(g.x, go + 0);
    __builtin_nontemporal_store(g.y, go + 1);

    // block-reduce lsum (4 waves) -> per-block partial
    for (int sh = 32; sh > 0; sh >>= 1) lsum += __shfl_down(lsum, sh);
    __shared__ float red[4];
    if ((t & 63) == 0) red[t >> 6] = lsum;
    __syncthreads();
    if (t == 0) partials[blockIdx.x] = red[0] + red[1] + red[2] + red[3];
}

__global__ void k_loss(const float* __restrict__ partials, float* __restrict__ out) {
    __shared__ float s[256];
    int t = threadIdx.x;
    float v = 0.f;
    for (int i = t; i < NBLK; i += 256) v += partials[i];
    s[t] = v;
    __syncthreads();
    for (int off = 128; off > 0; off >>= 1) {
        if (t < off) s[t] += s[t + off];
        __syncthreads();
    }
    if (t == 0) out[0] = 0.5f * sqrtf(s[0]) / (float)NBATCH;
}

extern "C" void kernel_launch(void* const* d_in, const int* in_sizes, int n_in,
                              void* d_out, int out_size, void* d_ws, size_t ws_size,
                              hipStream_t stream) {
    const int*   y       = (const int*)d_in[0];
    const float* feat    = (const float*)d_in[1];
    const float* centers = (const float*)d_in[2];
    float* out = (float*)d_out;
    float* partials = (float*)d_ws;   // 4000 floats, fully rewritten each call

    k_main<<<NBLK, 256, 0, stream>>>(y, feat, centers, out + 1, partials);
    k_loss<<<1, 256, 0, stream>>>(partials, out);
}

// Round 10
// 29.223 us; speedup vs baseline: 1.0817x; 1.0817x over previous
//
#include <hip/hip_runtime.h>
#include <math.h>

#define NC     1000
#define NBLK   4000     // 1000 classes x 4 column-quarters
#define DIM    2048
#define QCOLS  512
#define NBATCH 8192
#define MAXN   1024     // sidx capacity; true max class count ~25 (Poisson(8.2))

typedef float f32x4 __attribute__((ext_vector_type(4)));
typedef int   i32x4 __attribute__((ext_vector_type(4)));

// Grid: 4000 blocks = 1000 classes x 4 col-quarters; 128 threads (2 waves).
// 16 blocks/CU resident -> full 32-wave occupancy AND fine-grained static
// balance (per-CU sum over ~16 classes: +3sigma ~ +26% vs +37% at 8).
// Thread t of block (c,q) owns cols q*512 + [4t, 4t+4)  (f32x4, 16B/lane).
__global__ __launch_bounds__(128, 8) void k_main(
        const int*   __restrict__ y,
        const float* __restrict__ feat,
        const float* __restrict__ centers,
        float* __restrict__ grad_out,     // d_out + 1 (4B-aligned only)
        float* __restrict__ partials) {   // [4000]
    const int c = blockIdx.x >> 2;
    const int q = blockIdx.x & 3;
    const int t = threadIdx.x;
    const int col = q * QCOLS + 4 * t;

    const f32x4 cen = *(const f32x4*)(centers + (size_t)c * DIM + col);

    __shared__ unsigned short sidx[MAXN];
    __shared__ int scur;
    if (t == 0) scur = 0;
    __syncthreads();

    // scan y (L2/L3-resident): 16 int4 per thread
    const i32x4* y4 = (const i32x4*)y;
    for (int j = t; j < NBATCH / 4; j += 128) {
        i32x4 v = y4[j];
        int base = 4 * j;
        if (v.x == c) sidx[atomicAdd(&scur, 1) & (MAXN - 1)] = (unsigned short)(base + 0);
        if (v.y == c) sidx[atomicAdd(&scur, 1) & (MAXN - 1)] = (unsigned short)(base + 1);
        if (v.z == c) sidx[atomicAdd(&scur, 1) & (MAXN - 1)] = (unsigned short)(base + 2);
        if (v.w == c) sidx[atomicAdd(&scur, 1) & (MAXN - 1)] = (unsigned short)(base + 3);
    }
    __syncthreads();
    const int n = scur;

    f32x4 acc = (f32x4)(0.f);
    f32x4 sq  = (f32x4)(0.f);

    int r = 0;
    for (; r + 8 <= n; r += 8) {
        int i0 = sidx[r+0], i1 = sidx[r+1], i2 = sidx[r+2], i3 = sidx[r+3];
        int i4 = sidx[r+4], i5 = sidx[r+5], i6 = sidx[r+6], i7 = sidx[r+7];
        f32x4 v0 = *(const f32x4*)(feat + (size_t)i0 * DIM + col);
        f32x4 v1 = *(const f32x4*)(feat + (size_t)i1 * DIM + col);
        f32x4 v2 = *(const f32x4*)(feat + (size_t)i2 * DIM + col);
        f32x4 v3 = *(const f32x4*)(feat + (size_t)i3 * DIM + col);
        f32x4 v4 = *(const f32x4*)(feat + (size_t)i4 * DIM + col);
        f32x4 v5 = *(const f32x4*)(feat + (size_t)i5 * DIM + col);
        f32x4 v6 = *(const f32x4*)(feat + (size_t)i6 * DIM + col);
        f32x4 v7 = *(const f32x4*)(feat + (size_t)i7 * DIM + col);
        acc += v0 + v1 + v2 + v3 + v4 + v5 + v6 + v7;
        f32x4 d0 = v0 - cen, d1 = v1 - cen, d2 = v2 - cen, d3 = v3 - cen;
        f32x4 d4 = v4 - cen, d5 = v5 - cen, d6 = v6 - cen, d7 = v7 - cen;
        sq += d0*d0 + d1*d1 + d2*d2 + d3*d3 + d4*d4 + d5*d5 + d6*d6 + d7*d7;
    }
    for (; r < n; ++r) {
        f32x4 v0 = *(const f32x4*)(feat + (size_t)sidx[r] * DIM + col);
        acc += v0;
        f32x4 d0 = v0 - cen;
        sq += d0 * d0;
    }
    float lsum = sq.x + sq.y + sq.z + sq.w;

    // grad = coeff * (centers - mean); zero when n == 0
    f32x4 g = (f32x4)(0.f);
    if (n > 0) {
        float fn = (float)n;
        float coeff = fn / (1.0f + fn);
        g = coeff * (cen - acc * (1.0f / fn));
    }
    float* go = grad_out + (size_t)c * DIM + col;   // odd base -> scalar stores
    go[0] = g.x; go[1] = g.y; go[2] = g.z; go[3] = g.w;

    // block-reduce lsum (2 waves) -> per-block partial
    for (int sh = 32; sh > 0; sh >>= 1) lsum += __shfl_down(lsum, sh);
    __shared__ float red[2];
    if ((t & 63) == 0) red[t >> 6] = lsum;
    __syncthreads();
    if (t == 0) partials[blockIdx.x] = red[0] + red[1];
}

__global__ void k_loss(const float* __restrict__ partials, float* __restrict__ out) {
    __shared__ float s[256];
    int t = threadIdx.x;
    float v = 0.f;
    for (int i = t; i < NBLK; i += 256) v += partials[i];
    s[t] = v;
    __syncthreads();
    for (int off = 128; off > 0; off >>= 1) {
        if (t < off) s[t] += s[t + off];
        __syncthreads();
    }
    if (t == 0) out[0] = 0.5f * sqrtf(s[0]) / (float)NBATCH;
}

extern "C" void kernel_launch(void* const* d_in, const int* in_sizes, int n_in,
                              void* d_out, int out_size, void* d_ws, size_t ws_size,
                              hipStream_t stream) {
    const int*   y       = (const int*)d_in[0];
    const float* feat    = (const float*)d_in[1];
    const float* centers = (const float*)d_in[2];
    float* out = (float*)d_out;
    float* partials = (float*)d_ws;   // 4000 floats, fully rewritten each call

    k_main<<<NBLK, 128, 0, stream>>>(y, feat, centers, out + 1, partials);
    k_loss<<<1, 256, 0, stream>>>(partials, out);
}

// Round 11
// 24.184 us; speedup vs baseline: 1.3071x; 1.2084x over previous
//
#include <hip/hip_runtime.h>
#include <math.h>

#define NC     1000
#define NBLK   2000     // 2 column-half blocks per class
#define DIM    2048
#define HALF   1024
#define NBATCH 8192

typedef float f32x4 __attribute__((ext_vector_type(4)));
typedef int   i32x4 __attribute__((ext_vector_type(4)));

// EXACT R4 structure; single variable changed: nontemporal -> plain loads/stores
// (L3-retention test: 84 MB working set fits the 256 MB Infinity Cache across
// graph replays; NT hints may be defeating that).
// Grid: 2000 blocks = 1000 classes x 2 column halves; 256 threads.
// Thread t of block (c,h) owns cols h*1024 + [4t, 4t+4).
__global__ __launch_bounds__(256) void k_main(
        const int*   __restrict__ y,
        const float* __restrict__ feat,
        const float* __restrict__ centers,
        float* __restrict__ grad_out,     // d_out + 1 (4B-aligned only)
        float* __restrict__ partials) {   // [2000]
    const int c = blockIdx.x >> 1;
    const int h = blockIdx.x & 1;
    const int t = threadIdx.x;
    const int col = h * HALF + t * 4;

    const f32x4 cen = *(const f32x4*)(centers + (size_t)c * DIM + col);

    __shared__ unsigned short sidx[NBATCH];   // 16 KB worst case
    __shared__ int scur;
    if (t == 0) scur = 0;
    __syncthreads();

    // vectorized scan of y: 8192 ints as 2048 int4, 8 per thread
    const i32x4* y4 = (const i32x4*)y;
    for (int j = t; j < NBATCH / 4; j += 256) {
        i32x4 v = y4[j];
        int base = 4 * j;
        if (v.x == c) sidx[atomicAdd(&scur, 1)] = (unsigned short)(base + 0);
        if (v.y == c) sidx[atomicAdd(&scur, 1)] = (unsigned short)(base + 1);
        if (v.z == c) sidx[atomicAdd(&scur, 1)] = (unsigned short)(base + 2);
        if (v.w == c) sidx[atomicAdd(&scur, 1)] = (unsigned short)(base + 3);
    }
    __syncthreads();
    const int n = scur;

    f32x4 acc = (f32x4)(0.f);
    float lsum = 0.f;

    int r = 0;
    for (; r + 4 <= n; r += 4) {
        int i0 = sidx[r], i1 = sidx[r+1], i2 = sidx[r+2], i3 = sidx[r+3];
        f32x4 v0 = *(const f32x4*)(feat + (size_t)i0 * DIM + col);
        f32x4 v1 = *(const f32x4*)(feat + (size_t)i1 * DIM + col);
        f32x4 v2 = *(const f32x4*)(feat + (size_t)i2 * DIM + col);
        f32x4 v3 = *(const f32x4*)(feat + (size_t)i3 * DIM + col);
        acc += v0 + v1 + v2 + v3;
        f32x4 d0 = v0 - cen, d1 = v1 - cen, d2 = v2 - cen, d3 = v3 - cen;
        f32x4 sq = d0 * d0 + d1 * d1 + d2 * d2 + d3 * d3;
        lsum += sq.x + sq.y + sq.z + sq.w;
    }
    for (; r < n; ++r) {
        int i0 = sidx[r];
        f32x4 v0 = *(const f32x4*)(feat + (size_t)i0 * DIM + col);
        acc += v0;
        f32x4 d0 = v0 - cen;
        f32x4 sq = d0 * d0;
        lsum += sq.x + sq.y + sq.z + sq.w;
    }

    // grad = coeff * (centers - mean); coeff = n/(1+n); zero when n == 0
    f32x4 g = (f32x4)(0.f);
    if (n > 0) {
        float fn = (float)n;
        float inv = 1.0f / fn;
        float coeff = fn / (1.0f + fn);
        g = coeff * (cen - acc * inv);
    }
    float* go = grad_out + (size_t)c * DIM + col;   // odd base -> scalar stores
    go[0] = g.x; go[1] = g.y; go[2] = g.z; go[3] = g.w;

    // block-reduce lsum (4 waves)
    for (int sh = 32; sh > 0; sh >>= 1) lsum += __shfl_down(lsum, sh);
    __shared__ float red[4];
    if ((t & 63) == 0) red[t >> 6] = lsum;
    __syncthreads();
    if (t == 0) partials[blockIdx.x] = red[0] + red[1] + red[2] + red[3];
}

__global__ void k_loss(const float* __restrict__ partials, float* __restrict__ out) {
    __shared__ float s[256];
    int t = threadIdx.x;
    float v = 0.f;
    for (int i = t; i < NBLK; i += 256) v += partials[i];
    s[t] = v;
    __syncthreads();
    for (int off = 128; off > 0; off >>= 1) {
        if (t < off) s[t] += s[t + off];
        __syncthreads();
    }
    if (t == 0) out[0] = 0.5f * sqrtf(s[0]) / (float)NBATCH;
}

extern "C" void kernel_launch(void* const* d_in, const int* in_sizes, int n_in,
                              void* d_out, int out_size, void* d_ws, size_t ws_size,
                              hipStream_t stream) {
    const int*   y       = (const int*)d_in[0];
    const float* feat    = (const float*)d_in[1];
    const float* centers = (const float*)d_in[2];
    float* out = (float*)d_out;
    float* partials = (float*)d_ws;   // 2000 floats, fully rewritten each call

    k_main<<<NBLK, 256, 0, stream>>>(y, feat, centers, out + 1, partials);
    k_loss<<<1, 256, 0, stream>>>(partials, out);
}